// Round 14
// baseline (420.348 us; speedup 1.0000x reference)
//
#include <hip/hip_runtime.h>
#include <hip/hip_bf16.h>
#include <math.h>

#define L_SEQ 2048
#define B_SZ 2
#define D_MODEL 768
#define D_INNER 1536
#define D_STATE 16
#define DT_RANK 48
#define TC 32
#define NC (L_SEQ / TC)          // 64 chunks
#define NDG (D_INNER / 256)      // 6 d-groups
#define NSPL 4
#define KCH (D_INNER / NSPL)     // 384

typedef short bf16x8 __attribute__((ext_vector_type(8)));
typedef float f32x4 __attribute__((ext_vector_type(4)));

#define GLOAD16(g, l) __builtin_amdgcn_global_load_lds( \
    (const __attribute__((address_space(1))) unsigned*)(g), \
    (__attribute__((address_space(3))) unsigned*)(l), 16, 0, 0)

static __device__ __forceinline__ float siluf(float v) {
  return v / (1.0f + __expf(-v));
}
static __device__ __forceinline__ float softplusf(float v) {
  return fmaxf(v, 0.0f) + log1pf(__expf(-fabsf(v)));
}
static __device__ __forceinline__ unsigned short f2bf_rn(float v) {
  unsigned u = __float_as_uint(v);
  u = (u + 0x7fff + ((u >> 16) & 1)) >> 16;
  return (unsigned short)u;
}
static __device__ __forceinline__ float bf2f(unsigned short v) {
  return __uint_as_float((unsigned)v << 16);
}
// 4-way-split dt dot product over one dbl row
static __device__ __forceinline__ float dtdot48(const float* __restrict__ br,
                                                const float* __restrict__ wreg) {
  float a0 = 0.f, a1 = 0.f, a2 = 0.f, a3 = 0.f;
  #pragma unroll
  for (int q = 0; q < 3; ++q) {
    float4 v0 = *(const float4*)(br + q * 16 + 0);
    float4 v1 = *(const float4*)(br + q * 16 + 4);
    float4 v2 = *(const float4*)(br + q * 16 + 8);
    float4 v3 = *(const float4*)(br + q * 16 + 12);
    const float* w = wreg + q * 16;
    a0 = fmaf(v0.x, w[0], a0);  a0 = fmaf(v0.y, w[1], a0);
    a0 = fmaf(v0.z, w[2], a0);  a0 = fmaf(v0.w, w[3], a0);
    a1 = fmaf(v1.x, w[4], a1);  a1 = fmaf(v1.y, w[5], a1);
    a1 = fmaf(v1.z, w[6], a1);  a1 = fmaf(v1.w, w[7], a1);
    a2 = fmaf(v2.x, w[8], a2);  a2 = fmaf(v2.y, w[9], a2);
    a2 = fmaf(v2.z, w[10], a2); a2 = fmaf(v2.w, w[11], a2);
    a3 = fmaf(v3.x, w[12], a3); a3 = fmaf(v3.y, w[13], a3);
    a3 = fmaf(v3.z, w[14], a3); a3 = fmaf(v3.w, w[15], a3);
  }
  return (a0 + a1) + (a2 + a3);
}

// -------- fused fp32 -> bf16 hi/lo conversion for all 7 tensors -----------
__global__ __launch_bounds__(256) void cvt_all(
    const float* __restrict__ s_h,  unsigned short* __restrict__ hh,  unsigned short* __restrict__ hl,
    const float* __restrict__ s_w0, unsigned short* __restrict__ w0h, unsigned short* __restrict__ w0l,
    const float* __restrict__ s_w1, unsigned short* __restrict__ w1h, unsigned short* __restrict__ w1l,
    const float* __restrict__ s_o0, unsigned short* __restrict__ o0h, unsigned short* __restrict__ o0l,
    const float* __restrict__ s_o1, unsigned short* __restrict__ o1h, unsigned short* __restrict__ o1l,
    const float* __restrict__ s_x0, unsigned short* __restrict__ x0h, unsigned short* __restrict__ x0l,
    const float* __restrict__ s_x1, unsigned short* __restrict__ x1h, unsigned short* __restrict__ x1l)
{
  long j = (long)blockIdx.x * 256 + threadIdx.x;   // float4 index
  const long N0 = 786432, N1 = 589824, N2 = 589824, N3 = 294912, N4 = 294912, N5 = 30720;
  const float* src; unsigned short *dh, *dl;
  if (j < N0) { src = s_h; dh = hh; dl = hl; }
  else if ((j -= N0) < N1) { src = s_w0; dh = w0h; dl = w0l; }
  else if ((j -= N1) < N2) { src = s_w1; dh = w1h; dl = w1l; }
  else if ((j -= N2) < N3) { src = s_o0; dh = o0h; dl = o0l; }
  else if ((j -= N3) < N4) { src = s_o1; dh = o1h; dl = o1l; }
  else if ((j -= N4) < N5) { src = s_x0; dh = x0h; dl = x0l; }
  else { j -= N5; src = s_x1; dh = x1h; dl = x1l; }
  float4 v = ((const float4*)src)[j];
  float vv[4] = {v.x, v.y, v.z, v.w};
  unsigned short h4[4], l4[4];
  #pragma unroll
  for (int e = 0; e < 4; ++e) {
    unsigned short hv = f2bf_rn(vv[e]);
    h4[e] = hv;
    l4[e] = f2bf_rn(vv[e] - bf2f(hv));
  }
  uint2 ph, pl;
  ph.x = (unsigned)h4[0] | ((unsigned)h4[1] << 16);
  ph.y = (unsigned)h4[2] | ((unsigned)h4[3] << 16);
  pl.x = (unsigned)l4[0] | ((unsigned)l4[1] << 16);
  pl.y = (unsigned)l4[2] | ((unsigned)l4[3] << 16);
  *(uint2*)&dh[j * 4] = ph;
  *(uint2*)&dl[j * 4] = pl;
}

// -------- in_proj: bf16-plane MFMA GEMM, global_load_lds staging ----------
__global__ __launch_bounds__(256) void gemm_inproj(
    const unsigned short* __restrict__ hh, const unsigned short* __restrict__ hl,
    const unsigned short* __restrict__ w0h, const unsigned short* __restrict__ w0l,
    const unsigned short* __restrict__ w1h, const unsigned short* __restrict__ w1l,
    float* __restrict__ xpre, float* __restrict__ zbuf)
{
  __shared__ unsigned short Ah[128 * 32], Al[128 * 32];
  __shared__ unsigned short Wh[128 * 32], Wl[128 * 32];
  const long S1 = (long)B_SZ * L_SEQ * D_INNER;
  const int tid = threadIdx.x;
  const int lane = tid & 63, w = tid >> 6;
  int bid = blockIdx.x;
  int swz = (bid & 7) * 192 + (bid >> 3);
  int dir = swz / 768;
  int rem = swz - dir * 768;
  int mb = rem / 24, nb = rem - (rem / 24) * 24;
  const int m0 = mb * 128, n0 = nb * 128;
  const unsigned short* Whp = dir ? w1h : w0h;
  const unsigned short* Wlp = dir ? w1l : w0l;
  const int ksl = (lane & 3) ^ ((lane >> 3) & 3);
  long aoff[2], woff[2];
  int ldsc[2];
  #pragma unroll
  for (int qq = 0; qq < 2; ++qq) {
    int cq = w * 2 + qq;
    int r = cq * 16 + (lane >> 2);
    int mr = m0 + r;
    int row = dir ? ((mr & ~(L_SEQ - 1)) | ((L_SEQ - 1) - (mr & (L_SEQ - 1)))) : mr;
    aoff[qq] = (long)row * D_MODEL + 8 * ksl;
    woff[qq] = (long)(n0 + r) * D_MODEL + 8 * ksl;
    ldsc[qq] = cq * 512;
  }
  f32x4 acc[4][4];
  #pragma unroll
  for (int i = 0; i < 4; ++i)
    #pragma unroll
    for (int j = 0; j < 4; ++j) acc[i][j] = (f32x4){0.f, 0.f, 0.f, 0.f};
  const int fr = lane & 15, sl = lane >> 4;
  const int wr = w >> 1, wc = w & 1;
  int roffA[4], roffW[4];
  #pragma unroll
  for (int f = 0; f < 4; ++f) {
    int rA = wr * 64 + f * 16 + fr;
    roffA[f] = rA * 32 + ((sl ^ ((rA >> 1) & 3)) * 8);
    int rW = wc * 64 + f * 16 + fr;
    roffW[f] = rW * 32 + ((sl ^ ((rW >> 1) & 3)) * 8);
  }
  for (int k0 = 0; k0 < D_MODEL; k0 += 32) {
    __syncthreads();
    #pragma unroll
    for (int qq = 0; qq < 2; ++qq) {
      GLOAD16(hh + aoff[qq] + k0, &Ah[ldsc[qq]]);
      GLOAD16(hl + aoff[qq] + k0, &Al[ldsc[qq]]);
      GLOAD16(Whp + woff[qq] + k0, &Wh[ldsc[qq]]);
      GLOAD16(Wlp + woff[qq] + k0, &Wl[ldsc[qq]]);
    }
    __syncthreads();
    bf16x8 afh[4], afl[4];
    #pragma unroll
    for (int f = 0; f < 4; ++f) {
      afh[f] = *(const bf16x8*)&Ah[roffA[f]];
      afl[f] = *(const bf16x8*)&Al[roffA[f]];
    }
    #pragma unroll
    for (int fj = 0; fj < 4; ++fj) {
      bf16x8 wfh = *(const bf16x8*)&Wh[roffW[fj]];
      bf16x8 wfl = *(const bf16x8*)&Wl[roffW[fj]];
      #pragma unroll
      for (int fi = 0; fi < 4; ++fi) {
        acc[fi][fj] = __builtin_amdgcn_mfma_f32_16x16x32_bf16(afh[fi], wfh, acc[fi][fj], 0, 0, 0);
        acc[fi][fj] = __builtin_amdgcn_mfma_f32_16x16x32_bf16(afh[fi], wfl, acc[fi][fj], 0, 0, 0);
        acc[fi][fj] = __builtin_amdgcn_mfma_f32_16x16x32_bf16(afl[fi], wfh, acc[fi][fj], 0, 0, 0);
      }
    }
  }
  float* xq = xpre + (long)dir * S1;
  float* zq = zbuf + (long)dir * S1;
  const int fcol = lane & 15, rgrp = lane >> 4;
  #pragma unroll
  for (int fi = 0; fi < 4; ++fi) {
    #pragma unroll
    for (int j = 0; j < 4; ++j) {
      int row = m0 + wr * 64 + fi * 16 + rgrp * 4 + j;
      #pragma unroll
      for (int fj = 0; fj < 4; ++fj) {
        int n = n0 + wc * 64 + fj * 16 + fcol;
        float v = acc[fi][fj][j];
        if (n < D_INNER) xq[(long)row * D_INNER + n] = v;
        else             zq[(long)row * D_INNER + (n - D_INNER)] = v;
      }
    }
  }
}

// -------- xproj: plane MFMA, N=80 padded to 128, split-K x4 ---------------
__global__ __launch_bounds__(256) void xproj_mfma(
    const unsigned short* __restrict__ xh, const unsigned short* __restrict__ xl,
    const unsigned short* __restrict__ x0h, const unsigned short* __restrict__ x0l,
    const unsigned short* __restrict__ x1h, const unsigned short* __restrict__ x1l,
    float* __restrict__ partial)   // [2*NSPL][4096][80]
{
  __shared__ unsigned short Ah[128 * 32], Al[128 * 32];
  __shared__ unsigned short Wh[128 * 32], Wl[128 * 32];
  const long S1 = (long)B_SZ * L_SEQ * D_INNER;
  const int tid = threadIdx.x;
  const int lane = tid & 63, w = tid >> 6;
  int bid = blockIdx.x;
  int dir = bid >> 7;
  int kz = (bid >> 5) & 3;
  int mb = bid & 31;
  const int m0 = mb * 128;
  const int kbase = kz * KCH;
  const unsigned short* Ahp = xh + (long)dir * S1;
  const unsigned short* Alp = xl + (long)dir * S1;
  const unsigned short* Whp = dir ? x1h : x0h;
  const unsigned short* Wlp = dir ? x1l : x0l;
  const int ksl = (lane & 3) ^ ((lane >> 3) & 3);
  long aoff[2], woff[2];
  int ldsc[2], cqv[2];
  #pragma unroll
  for (int qq = 0; qq < 2; ++qq) {
    int cq = w * 2 + qq;
    int r = cq * 16 + (lane >> 2);
    aoff[qq] = (long)(m0 + r) * D_INNER + 8 * ksl + kbase;
    woff[qq] = (long)r * D_INNER + 8 * ksl + kbase;
    ldsc[qq] = cq * 512;
    cqv[qq] = cq;
  }
  for (int i = tid; i < 48 * 32; i += 256) { Wh[80 * 32 + i] = 0; Wl[80 * 32 + i] = 0; }
  f32x4 acc[4][4];
  #pragma unroll
  for (int i = 0; i < 4; ++i)
    #pragma unroll
    for (int j = 0; j < 4; ++j) acc[i][j] = (f32x4){0.f, 0.f, 0.f, 0.f};
  const int fr = lane & 15, sl = lane >> 4;
  const int wr = w >> 1, wc = w & 1;
  int roffA[4], roffW[4];
  #pragma unroll
  for (int f = 0; f < 4; ++f) {
    int rA = wr * 64 + f * 16 + fr;
    roffA[f] = rA * 32 + ((sl ^ ((rA >> 1) & 3)) * 8);
    int rW = wc * 64 + f * 16 + fr;
    roffW[f] = rW * 32 + ((sl ^ ((rW >> 1) & 3)) * 8);
  }
  for (int k0 = 0; k0 < KCH; k0 += 32) {
    __syncthreads();
    #pragma unroll
    for (int qq = 0; qq < 2; ++qq) {
      GLOAD16(Ahp + aoff[qq] + k0, &Ah[ldsc[qq]]);
      GLOAD16(Alp + aoff[qq] + k0, &Al[ldsc[qq]]);
      if (cqv[qq] < 5) {
        GLOAD16(Whp + woff[qq] + k0, &Wh[ldsc[qq]]);
        GLOAD16(Wlp + woff[qq] + k0, &Wl[ldsc[qq]]);
      }
    }
    __syncthreads();
    bf16x8 afh[4], afl[4];
    #pragma unroll
    for (int f = 0; f < 4; ++f) {
      afh[f] = *(const bf16x8*)&Ah[roffA[f]];
      afl[f] = *(const bf16x8*)&Al[roffA[f]];
    }
    #pragma unroll
    for (int fj = 0; fj < 4; ++fj) {
      bf16x8 wfh = *(const bf16x8*)&Wh[roffW[fj]];
      bf16x8 wfl = *(const bf16x8*)&Wl[roffW[fj]];
      #pragma unroll
      for (int fi = 0; fi < 4; ++fi) {
        acc[fi][fj] = __builtin_amdgcn_mfma_f32_16x16x32_bf16(afh[fi], wfh, acc[fi][fj], 0, 0, 0);
        acc[fi][fj] = __builtin_amdgcn_mfma_f32_16x16x32_bf16(afh[fi], wfl, acc[fi][fj], 0, 0, 0);
        acc[fi][fj] = __builtin_amdgcn_mfma_f32_16x16x32_bf16(afl[fi], wfh, acc[fi][fj], 0, 0, 0);
      }
    }
  }
  float* P = partial + (long)(dir * NSPL + kz) * (B_SZ * L_SEQ) * 80;
  const int fcol = lane & 15, rgrp = lane >> 4;
  #pragma unroll
  for (int fi = 0; fi < 4; ++fi) {
    #pragma unroll
    for (int j = 0; j < 4; ++j) {
      int row = m0 + wr * 64 + fi * 16 + rgrp * 4 + j;
      #pragma unroll
      for (int fj = 0; fj < 4; ++fj) {
        int n = wc * 64 + fj * 16 + fcol;
        if (n < 80) P[(long)row * 80 + n] = acc[fi][fj][j];
      }
    }
  }
}

__global__ __launch_bounds__(256) void xproj_reduce(
    const float* __restrict__ partial, float* __restrict__ dbl)
{
  long idx = (long)blockIdx.x * 256 + threadIdx.x;
  const long plane = (long)B_SZ * L_SEQ * 80;
  long dir = idx / plane;
  long rc = idx % plane;
  const float* P = partial + dir * NSPL * plane + rc;
  float s = 0.f;
  #pragma unroll
  for (int z = 0; z < NSPL; ++z) s += P[z * plane];
  dbl[idx] = s;
}

// -------- dtproj: slot-dense dt precompute; FULL coverage (12x128 grid) ---
__global__ __launch_bounds__(256) void dtproj_k(
    const float* __restrict__ dbl,
    const float* __restrict__ dtw_f, const float* __restrict__ dtw_r,
    const float* __restrict__ dtb_f, const float* __restrict__ dtb_r,
    float* __restrict__ dt)   // [2][B*L][D_INNER]
{
  const int tid = threadIdx.x;
  const int dgrp = blockIdx.x;            // 0..11 = dir*NDG + dg
  const int dir = dgrp / NDG;
  const int d = (dgrp % NDG) * 256 + tid;
  const int rc = blockIdx.y;              // 0..127, 32 rows each -> 4096 rows/dir
  const float* dtw = dir ? dtw_r : dtw_f;
  const float dtbv = (dir ? dtb_r : dtb_f)[d];
  float wreg[48];
  #pragma unroll
  for (int q = 0; q < 12; ++q)
    *(float4*)&wreg[q * 4] = *(const float4*)&dtw[d * DT_RANK + q * 4];
  const long rowbase = (long)dir * (B_SZ * L_SEQ) + (long)rc * 32;
  for (int r = 0; r < 32; ++r) {
    long row = rowbase + r;
    const float* br = dbl + row * 80;
    float v = softplusf(dtdot48(br, wreg) + dtbv);
    dt[row * D_INNER + d] = v;
  }
}

// -------- out_proj: all-plane MFMA; split-(dir,K); GLOAD16 staging --------
__global__ __launch_bounds__(256) void gemm_outproj_pl(
    const unsigned short* __restrict__ yh, const unsigned short* __restrict__ yl,
    const unsigned short* __restrict__ o0h, const unsigned short* __restrict__ o0l,
    const unsigned short* __restrict__ o1h, const unsigned short* __restrict__ o1l,
    float* __restrict__ partial)   // [4][4096][768], plane = dir*2+ks
{
  __shared__ unsigned short Ah[128 * 32], Al[128 * 32];
  __shared__ unsigned short Wh[128 * 32], Wl[128 * 32];
  const long S1 = (long)B_SZ * L_SEQ * D_INNER;
  const int tid = threadIdx.x;
  const int lane = tid & 63, w = tid >> 6;
  int bid = blockIdx.x;
  int swz = (bid & 7) * 96 + (bid >> 3);
  int dir = swz / 384;
  int r1 = swz - dir * 384;
  int ks = r1 / 192;
  int r2 = r1 - ks * 192;
  int mb = r2 / 6, nb = r2 - (r2 / 6) * 6;
  const int m0 = mb * 128, n0 = nb * 128;
  const int kbase = ks * (D_INNER / 2);
  const unsigned short* Ahp = yh + (long)dir * S1;
  const unsigned short* Alp = yl + (long)dir * S1;
  const unsigned short* Whp = dir ? o1h : o0h;
  const unsigned short* Wlp = dir ? o1l : o0l;
  const int ksl = (lane & 3) ^ ((lane >> 3) & 3);
  long aoff[2], woff[2];
  int ldsc[2];
  #pragma unroll
  for (int qq = 0; qq < 2; ++qq) {
    int cq = w * 2 + qq;
    int r = cq * 16 + (lane >> 2);
    int mr = m0 + r;
    int row = dir ? ((mr & ~(L_SEQ - 1)) | ((L_SEQ - 1) - (mr & (L_SEQ - 1)))) : mr;
    aoff[qq] = (long)row * D_INNER + 8 * ksl + kbase;
    woff[qq] = (long)(n0 + r) * D_INNER + 8 * ksl + kbase;
    ldsc[qq] = cq * 512;
  }
  f32x4 acc[4][4];
  #pragma unroll
  for (int i = 0; i < 4; ++i)
    #pragma unroll
    for (int j = 0; j < 4; ++j) acc[i][j] = (f32x4){0.f, 0.f, 0.f, 0.f};
  const int fr = lane & 15, sl = lane >> 4;
  const int wr = w >> 1, wc = w & 1;
  int roffA[4], roffW[4];
  #pragma unroll
  for (int f = 0; f < 4; ++f) {
    int rA = wr * 64 + f * 16 + fr;
    roffA[f] = rA * 32 + ((sl ^ ((rA >> 1) & 3)) * 8);
    int rW = wc * 64 + f * 16 + fr;
    roffW[f] = rW * 32 + ((sl ^ ((rW >> 1) & 3)) * 8);
  }
  for (int k0 = 0; k0 < D_INNER / 2; k0 += 32) {
    __syncthreads();
    #pragma unroll
    for (int qq = 0; qq < 2; ++qq) {
      GLOAD16(Ahp + aoff[qq] + k0, &Ah[ldsc[qq]]);
      GLOAD16(Alp + aoff[qq] + k0, &Al[ldsc[qq]]);
      GLOAD16(Whp + woff[qq] + k0, &Wh[ldsc[qq]]);
      GLOAD16(Wlp + woff[qq] + k0, &Wl[ldsc[qq]]);
    }
    __syncthreads();
    bf16x8 afh[4], afl[4];
    #pragma unroll
    for (int f = 0; f < 4; ++f) {
      afh[f] = *(const bf16x8*)&Ah[roffA[f]];
      afl[f] = *(const bf16x8*)&Al[roffA[f]];
    }
    #pragma unroll
    for (int fj = 0; fj < 4; ++fj) {
      bf16x8 wfh = *(const bf16x8*)&Wh[roffW[fj]];
      bf16x8 wfl = *(const bf16x8*)&Wl[roffW[fj]];
      #pragma unroll
      for (int fi = 0; fi < 4; ++fi) {
        acc[fi][fj] = __builtin_amdgcn_mfma_f32_16x16x32_bf16(afh[fi], wfh, acc[fi][fj], 0, 0, 0);
        acc[fi][fj] = __builtin_amdgcn_mfma_f32_16x16x32_bf16(afh[fi], wfl, acc[fi][fj], 0, 0, 0);
        acc[fi][fj] = __builtin_amdgcn_mfma_f32_16x16x32_bf16(afl[fi], wfh, acc[fi][fj], 0, 0, 0);
      }
    }
  }
  float* P = partial + (long)(dir * 2 + ks) * (B_SZ * L_SEQ) * D_MODEL;
  const int fcol = lane & 15, rgrp = lane >> 4;
  #pragma unroll
  for (int fi = 0; fi < 4; ++fi) {
    #pragma unroll
    for (int j = 0; j < 4; ++j) {
      int row = m0 + wr * 64 + fi * 16 + rgrp * 4 + j;
      #pragma unroll
      for (int fj = 0; fj < 4; ++fj) {
        int n = n0 + wc * 64 + fj * 16 + fcol;
        P[(long)row * D_MODEL + n] = acc[fi][fj][j];
      }
    }
  }
}

__global__ __launch_bounds__(256) void outproj_reduce(
    const float* __restrict__ partial, float* __restrict__ out)
{
  long i = (long)blockIdx.x * 256 + threadIdx.x;   // float4 index
  const long plane4 = (long)B_SZ * L_SEQ * D_MODEL / 4;  // 786432
  float4 a = ((const float4*)partial)[i];
  float4 b = ((const float4*)partial)[i + plane4];
  float4 c = ((const float4*)partial)[i + 2 * plane4];
  float4 d = ((const float4*)partial)[i + 3 * plane4];
  float4 s;
  s.x = (a.x + b.x) + (c.x + d.x);
  s.y = (a.y + b.y) + (c.y + d.y);
  s.z = (a.z + b.z) + (c.z + d.z);
  s.w = (a.w + b.w) + (c.w + d.w);
  ((float4*)out)[i] = s;
}

// -------- conv (w=4) + bias + silu -> bf16 planes; 4 timesteps/thread -----
__global__ __launch_bounds__(256) void conv_silu_pl4(
    const float* __restrict__ xpre,
    const float* __restrict__ w_f, const float* __restrict__ b_f,
    const float* __restrict__ w_r, const float* __restrict__ b_r,
    unsigned short* __restrict__ xh, unsigned short* __restrict__ xl)
{
  long i = (long)blockIdx.x * 256 + threadIdx.x;
  const int DQ = D_INNER / 4;                 // 384
  const long total = 2L * B_SZ * (L_SEQ / 4) * DQ;   // 786432
  if (i >= total) return;
  int dq = (int)(i % DQ);
  long rq = i / DQ;
  int t0 = (int)((rq & (L_SEQ / 4 - 1)) * 4);
  long rbase = (rq >> 9) * L_SEQ;
  int dir = (int)(rq >> 10);
  int d0 = dq * 4;
  const float* w  = dir ? w_r : w_f;
  const float* cb = dir ? b_r : b_f;
  float4 bias = *(const float4*)&cb[d0];
  float4 wc[4];
  #pragma unroll
  for (int c = 0; c < 4; ++c) wc[c] = *(const float4*)&w[(d0 + c) * 4];
  float4 xrow[7];
  #pragma unroll
  for (int j = 0; j < 7; ++j) {
    int tv = t0 + j - 3;
    if (tv >= 0) xrow[j] = *(const float4*)&xpre[(rbase + tv) * D_INNER + d0];
    else xrow[j] = (float4){0.f, 0.f, 0.f, 0.f};
  }
  #pragma unroll
  for (int u = 0; u < 4; ++u) {
    float4 a = bias;
    #pragma unroll
    for (int k = 0; k < 4; ++k) {
      float4 xv = xrow[u + k];
      a.x = fmaf(((const float*)&wc[0])[k], xv.x, a.x);
      a.y = fmaf(((const float*)&wc[1])[k], xv.y, a.y);
      a.z = fmaf(((const float*)&wc[2])[k], xv.z, a.z);
      a.w = fmaf(((const float*)&wc[3])[k], xv.w, a.w);
    }
    float vv[4] = {siluf(a.x), siluf(a.y), siluf(a.z), siluf(a.w)};
    unsigned short h4[4], l4[4];
    #pragma unroll
    for (int e = 0; e < 4; ++e) {
      unsigned short hv = f2bf_rn(vv[e]);
      h4[e] = hv;
      l4[e] = f2bf_rn(vv[e] - bf2f(hv));
    }
    uint2 ph, pl;
    ph.x = (unsigned)h4[0] | ((unsigned)h4[1] << 16);
    ph.y = (unsigned)h4[2] | ((unsigned)h4[3] << 16);
    pl.x = (unsigned)l4[0] | ((unsigned)l4[1] << 16);
    pl.y = (unsigned)l4[2] | ((unsigned)l4[3] << 16);
    long off = (rbase + t0 + u) * D_INNER + d0;
    *(uint2*)&xh[off] = ph;
    *(uint2*)&xl[off] = pl;
  }
}

// -------- scan pass 1: dt preloaded; stores local state S + sum(dt) -------
__global__ __launch_bounds__(256) void scan_mega1(
    const unsigned short* __restrict__ xh, const unsigned short* __restrict__ xl,
    const float* __restrict__ dbl, const float* __restrict__ dt,
    const float* __restrict__ A_log_f, const float* __restrict__ A_log_r,
    float* __restrict__ stateS, float* __restrict__ sdtb)
{
  const int tid = threadIdx.x;
  const int chunk = blockIdx.x / NDG;
  const int d = (blockIdx.x % NDG) * 256 + tid;
  const int b = blockIdx.y, dir = blockIdx.z;
  const float* A_log = dir ? A_log_r : A_log_f;
  float Arow[D_STATE];
  #pragma unroll
  for (int n = 0; n < D_STATE; ++n) Arow[n] = -expf(A_log[d * D_STATE + n]);
  float h[D_STATE];
  #pragma unroll
  for (int n = 0; n < D_STATE; ++n) h[n] = 0.f;
  float sdt = 0.f;
  const long rowbase = ((long)dir * B_SZ + b) * L_SEQ + (long)chunk * TC;
  __shared__ float bcs[TC][D_STATE];
  for (int i = tid; i < TC * D_STATE; i += 256) {
    int t = i >> 4, n = i & 15;
    bcs[t][n] = dbl[(rowbase + t) * 80 + 48 + n];
  }
  __syncthreads();
  for (int tj = 0; tj < TC; ++tj) {
    long off = (rowbase + tj) * D_INNER + d;
    float dtv = dt[off];
    float xv = bf2f(xh[off]) + bf2f(xl[off]);
    float dtx = dtv * xv;
    sdt += dtv;
    const float* bc = &bcs[tj][0];
    #pragma unroll
    for (int n = 0; n < D_STATE; ++n) {
      float dA = __expf(dtv * Arow[n]);
      h[n] = fmaf(h[n], dA, dtx * bc[n]);
    }
  }
  const long dirb = (long)dir * B_SZ + b;
  long base = ((dirb * NC + chunk) * D_INNER + d) * D_STATE;
  #pragma unroll
  for (int n = 0; n < D_STATE; ++n) stateS[base + n] = h[n];
  sdtb[(dirb * NC + chunk) * D_INNER + d] = sdt;
}

// -------- fused-dt fallback variant of pass 1 -----------------------------
__global__ __launch_bounds__(256, 3) void scan_mega1_f(
    const unsigned short* __restrict__ xh, const unsigned short* __restrict__ xl,
    const float* __restrict__ dbl,
    const float* __restrict__ dtw_f, const float* __restrict__ dtw_r,
    const float* __restrict__ dtb_f, const float* __restrict__ dtb_r,
    const float* __restrict__ A_log_f, const float* __restrict__ A_log_r,
    float* __restrict__ stateS, float* __restrict__ sdtb)
{
  const int tid = threadIdx.x;
  const int chunk = blockIdx.x / NDG;
  const int d = (blockIdx.x % NDG) * 256 + tid;
  const int b = blockIdx.y, dir = blockIdx.z;
  const float* A_log = dir ? A_log_r : A_log_f;
  const float* dtw   = dir ? dtw_r : dtw_f;
  const float dtbv   = (dir ? dtb_r : dtb_f)[d];
  float wreg[48];
  #pragma unroll
  for (int q = 0; q < 12; ++q)
    *(float4*)&wreg[q * 4] = *(const float4*)&dtw[d * DT_RANK + q * 4];
  float Arow[D_STATE];
  #pragma unroll
  for (int n = 0; n < D_STATE; ++n) Arow[n] = -expf(A_log[d * D_STATE + n]);
  float h[D_STATE];
  #pragma unroll
  for (int n = 0; n < D_STATE; ++n) h[n] = 0.f;
  float sdt = 0.f;
  const long rowbase = ((long)dir * B_SZ + b) * L_SEQ + (long)chunk * TC;
  for (int tj = 0; tj < TC; ++tj) {
    const float* br = dbl + (rowbase + tj) * 80;
    float dtv = softplusf(dtdot48(br, wreg) + dtbv);
    long off = (rowbase + tj) * D_INNER + d;
    float xv = bf2f(xh[off]) + bf2f(xl[off]);
    float dtx = dtv * xv;
    sdt += dtv;
    float bc[D_STATE];
    #pragma unroll
    for (int q = 0; q < 4; ++q)
      *(float4*)&bc[q * 4] = *(const float4*)(br + 48 + q * 4);
    #pragma unroll
    for (int n = 0; n < D_STATE; ++n) {
      float dA = __expf(dtv * Arow[n]);
      h[n] = fmaf(h[n], dA, dtx * bc[n]);
    }
  }
  const long dirb = (long)dir * B_SZ + b;
  long base = ((dirb * NC + chunk) * D_INNER + d) * D_STATE;
  #pragma unroll
  for (int n = 0; n < D_STATE; ++n) stateS[base + n] = h[n];
  sdtb[(dirb * NC + chunk) * D_INNER + d] = sdt;
}

// -------- fix-up: decay recomputed from A_log and sum(dt) -----------------
__global__ __launch_bounds__(256, 2) void scan_fix(
    float* __restrict__ stateS, const float* __restrict__ sdtb,
    const float* __restrict__ A_log_f, const float* __restrict__ A_log_r)
{
  const long idx = (long)blockIdx.x * 256 + threadIdx.x;  // 4 * D*16 threads
  const int DN = D_INNER * D_STATE;
  const long dirb = idx / DN;
  const int dn = (int)(idx % DN);
  const int d = dn >> 4, n = dn & 15;
  const float* A_log = (dirb >= B_SZ) ? A_log_r : A_log_f;
  const float Ar = -expf(A_log[d * D_STATE + n]);
  long base = dirb * NC * DN + dn;
  long sbase = dirb * NC * D_INNER + d;
  float S[NC], SD[NC];
  #pragma unroll
  for (int c = 0; c < NC; ++c) {
    S[c] = stateS[base + (long)c * DN];
    SD[c] = sdtb[sbase + (long)c * D_INNER];
  }
  float h = 0.f;
  #pragma unroll
  for (int c = 0; c < NC; ++c) {
    stateS[base + (long)c * DN] = h;
    h = fmaf(h, __expf(Ar * SD[c]), S[c]);
  }
}

// -------- scan pass 2: dt preloaded, B/C staged in LDS --------------------
__global__ __launch_bounds__(256) void scan_mega2(
    const unsigned short* __restrict__ xh, const unsigned short* __restrict__ xl,
    const float* __restrict__ dbl, const float* __restrict__ z,
    const float* __restrict__ dt,
    const float* __restrict__ A_log_f, const float* __restrict__ A_log_r,
    const float* __restrict__ Ds_f, const float* __restrict__ Ds_r,
    const float* __restrict__ stateS,
    unsigned short* __restrict__ yh, unsigned short* __restrict__ yl)
{
  const int tid = threadIdx.x;
  const int chunk = blockIdx.x / NDG;
  const int d = (blockIdx.x % NDG) * 256 + tid;
  const int b = blockIdx.y, dir = blockIdx.z;
  const float* A_log = dir ? A_log_r : A_log_f;
  const float Dd     = (dir ? Ds_r : Ds_f)[d];
  float Arow[D_STATE];
  #pragma unroll
  for (int n = 0; n < D_STATE; ++n) Arow[n] = -expf(A_log[d * D_STATE + n]);
  float h[D_STATE];
  long sbase = ((((long)dir * B_SZ + b) * NC + chunk) * D_INNER + d) * D_STATE;
  #pragma unroll
  for (int n = 0; n < D_STATE; ++n) h[n] = stateS[sbase + n];
  const long rowbase = ((long)dir * B_SZ + b) * L_SEQ + (long)chunk * TC;
  __shared__ float bcs[TC][2 * D_STATE];
  for (int i = tid; i < TC * 2 * D_STATE; i += 256) {
    int t = i >> 5, n = i & 31;
    bcs[t][n] = dbl[(rowbase + t) * 80 + 48 + n];
  }
  __syncthreads();
  for (int tj = 0; tj < TC; ++tj) {
    long off = (rowbase + tj) * D_INNER + d;
    float dtv = dt[off];
    float xv = bf2f(xh[off]) + bf2f(xl[off]);
    float zv = z[off];
    float dtx = dtv * xv;
    const float* bc = &bcs[tj][0];
    float y = 0.f;
    #pragma unroll
    for (int n = 0; n < D_STATE; ++n) {
      float dA = __expf(dtv * Arow[n]);
      h[n] = fmaf(h[n], dA, dtx * bc[n]);
      y = fmaf(h[n], bc[16 + n], y);
    }
    y = fmaf(xv, Dd, y);
    y *= siluf(zv);
    unsigned short hv = f2bf_rn(y);
    yh[off] = hv;
    yl[off] = f2bf_rn(y - bf2f(hv));
  }
}

// -------- fused-dt fallback variant of pass 2 -----------------------------
__global__ __launch_bounds__(256, 3) void scan_mega2_f(
    const unsigned short* __restrict__ xh, const unsigned short* __restrict__ xl,
    const float* __restrict__ dbl, const float* __restrict__ z,
    const float* __restrict__ dtw_f, const float* __restrict__ dtw_r,
    const float* __restrict__ dtb_f, const float* __restrict__ dtb_r,
    const float* __restrict__ A_log_f, const float* __restrict__ A_log_r,
    const float* __restrict__ Ds_f, const float* __restrict__ Ds_r,
    const float* __restrict__ stateS,
    unsigned short* __restrict__ yh, unsigned short* __restrict__ yl)
{
  const int tid = threadIdx.x;
  const int chunk = blockIdx.x / NDG;
  const int d = (blockIdx.x % NDG) * 256 + tid;
  const int b = blockIdx.y, dir = blockIdx.z;
  const float* A_log = dir ? A_log_r : A_log_f;
  const float* dtw   = dir ? dtw_r : dtw_f;
  const float dtbv   = (dir ? dtb_r : dtb_f)[d];
  const float Dd     = (dir ? Ds_r : Ds_f)[d];
  float wreg[48];
  #pragma unroll
  for (int q = 0; q < 12; ++q)
    *(float4*)&wreg[q * 4] = *(const float4*)&dtw[d * DT_RANK + q * 4];
  float Arow[D_STATE];
  #pragma unroll
  for (int n = 0; n < D_STATE; ++n) Arow[n] = -expf(A_log[d * D_STATE + n]);
  float h[D_STATE];
  long sbase = ((((long)dir * B_SZ + b) * NC + chunk) * D_INNER + d) * D_STATE;
  #pragma unroll
  for (int n = 0; n < D_STATE; ++n) h[n] = stateS[sbase + n];
  const long rowbase = ((long)dir * B_SZ + b) * L_SEQ + (long)chunk * TC;
  for (int tj = 0; tj < TC; ++tj) {
    const float* br = dbl + (rowbase + tj) * 80;
    float dtv = softplusf(dtdot48(br, wreg) + dtbv);
    long off = (rowbase + tj) * D_INNER + d;
    float xv = bf2f(xh[off]) + bf2f(xl[off]);
    float zv = z[off];
    float dtx = dtv * xv;
    float bc[2 * D_STATE];
    #pragma unroll
    for (int q = 0; q < 8; ++q)
      *(float4*)&bc[q * 4] = *(const float4*)(br + 48 + q * 4);
    float y = 0.f;
    #pragma unroll
    for (int n = 0; n < D_STATE; ++n) {
      float dA = __expf(dtv * Arow[n]);
      h[n] = fmaf(h[n], dA, dtx * bc[n]);
      y = fmaf(h[n], bc[16 + n], y);
    }
    y = fmaf(xv, Dd, y);
    y *= siluf(zv);
    unsigned short hv = f2bf_rn(y);
    yh[off] = hv;
    yl[off] = f2bf_rn(y - bf2f(hv));
  }
}

extern "C" void kernel_launch(void* const* d_in, const int* in_sizes, int n_in,
                              void* d_out, int out_size, void* d_ws, size_t ws_size,
                              hipStream_t stream) {
  const float* h        = (const float*)d_in[0];
  const float* in_proj[2] = {(const float*)d_in[1], (const float*)d_in[10]};
  const float* conv_w[2]  = {(const float*)d_in[2], (const float*)d_in[11]};
  const float* conv_b[2]  = {(const float*)d_in[3], (const float*)d_in[12]};
  const float* xproj[2]   = {(const float*)d_in[4], (const float*)d_in[13]};
  const float* dtw[2]     = {(const float*)d_in[5], (const float*)d_in[14]};
  const float* dtb[2]     = {(const float*)d_in[6], (const float*)d_in[15]};
  const float* A_log[2]   = {(const float*)d_in[7], (const float*)d_in[16]};
  const float* Dsk[2]     = {(const float*)d_in[8], (const float*)d_in[17]};
  const float* outp[2]    = {(const float*)d_in[9], (const float*)d_in[18]};
  float* out = (float*)d_out;
  float* ws = (float*)d_ws;

  const long S1 = (long)B_SZ * L_SEQ * D_INNER;   // 6,291,456
  const int M = B_SZ * L_SEQ;                     // 4096
  float* xpre  = ws;
  float* zbuf  = ws + 2 * S1;
  float* xconv = ws + 4 * S1;
  float* dbl   = ws + 6 * S1;
  float* base4 = dbl + 2L * M * 80;

  unsigned short* hh  = (unsigned short*)base4;             // 3,145,728 each
  unsigned short* hl  = hh + 3145728;
  unsigned short* w0h = hl + 3145728;                       // 2,359,296 each
  unsigned short* w0l = w0h + 2359296;
  unsigned short* w1h = w0l + 2359296;
  unsigned short* w1l = w1h + 2359296;
  unsigned short* o0h = w1l + 2359296;                      // 1,179,648 each
  unsigned short* o0l = o0h + 1179648;
  unsigned short* o1h = o0l + 1179648;
  unsigned short* o1l = o1h + 1179648;
  float* xpartial = base4;
  // NC=64 states with sdt trick: stS 6.29M fl + sdt 0.39M fl < 7.86M fl (o0h)
  float* stS  = base4;                                       // 6,291,456 fl
  float* sdtb = stS + 6291456;                               //   393,216 fl
  unsigned short* xw0h = (unsigned short*)dbl;              // 122,880 each
  unsigned short* xw0l = xw0h + 122880;
  unsigned short* xw1h = xw0l + 122880;
  unsigned short* xw1l = xw1h + 122880;
  unsigned short* xph = (unsigned short*)xconv;
  unsigned short* xpl = xph + 2 * S1;
  unsigned short* yh = (unsigned short*)xpre;
  unsigned short* yl = yh + 2 * S1;
  float* opartial = xconv;

  // dt buffer in EXTENDED workspace, past o1l; guarded by ws_size.
  float* dtbuf = base4 + 10223616;             // o1l end (20,447,232 ushorts)
  const long need_fl = (6 * S1) + 2L * M * 80 + 10223616 + 2 * S1;  // +dt
  const bool use_dt = (ws_size >= (size_t)need_fl * 4);

  dim3 blk(256);

  // 0. pre-convert h + all GEMM weights to bf16 hi/lo planes
  cvt_all<<<dim3(10224), blk, 0, stream>>>(
      h, hh, hl, in_proj[0], w0h, w0l, in_proj[1], w1h, w1l,
      outp[0], o0h, o0l, outp[1], o1h, o1l,
      xproj[0], xw0h, xw0l, xproj[1], xw1h, xw1l);

  // 1. in_proj (both dirs) -> x (pre-conv, fp32) and z
  gemm_inproj<<<dim3(1536), blk, 0, stream>>>(hh, hl, w0h, w0l, w1h, w1l, xpre, zbuf);

  // 2. conv + silu -> x bf16 hi/lo planes
  conv_silu_pl4<<<dim3(3072), blk, 0, stream>>>(
      xpre, conv_w[0], conv_b[0], conv_w[1], conv_b[1], xph, xpl);

  // 3. xproj (plane MFMA, split-K x4) -> partials -> dbl
  xproj_mfma<<<dim3(256), blk, 0, stream>>>(xph, xpl, xw0h, xw0l, xw1h, xw1l, xpartial);
  xproj_reduce<<<dim3((unsigned)(2L * M * 80 / 256)), blk, 0, stream>>>(xpartial, dbl);

  // 4+5. dt precompute (if ws allows) + chunked scan (TC=32, 1536 blocks)
  {
    dim3 grid1(NC * NDG, B_SZ, 2);
    long nfix = 2L * B_SZ * D_INNER * D_STATE;   // 98304 threads
    if (use_dt) {
      dtproj_k<<<dim3(12, 128), blk, 0, stream>>>(dbl, dtw[0], dtw[1], dtb[0], dtb[1], dtbuf);
      scan_mega1<<<grid1, blk, 0, stream>>>(xph, xpl, dbl, dtbuf,
          A_log[0], A_log[1], stS, sdtb);
      scan_fix<<<dim3((unsigned)(nfix / 256)), blk, 0, stream>>>(stS, sdtb, A_log[0], A_log[1]);
      scan_mega2<<<grid1, blk, 0, stream>>>(xph, xpl, dbl, zbuf, dtbuf,
          A_log[0], A_log[1], Dsk[0], Dsk[1], stS, yh, yl);
    } else {
      scan_mega1_f<<<grid1, blk, 0, stream>>>(xph, xpl, dbl,
          dtw[0], dtw[1], dtb[0], dtb[1], A_log[0], A_log[1], stS, sdtb);
      scan_fix<<<dim3((unsigned)(nfix / 256)), blk, 0, stream>>>(stS, sdtb, A_log[0], A_log[1]);
      scan_mega2_f<<<grid1, blk, 0, stream>>>(xph, xpl, dbl, zbuf,
          dtw[0], dtw[1], dtb[0], dtb[1], A_log[0], A_log[1],
          Dsk[0], Dsk[1], stS, yh, yl);
    }
  }
  // 6. out_proj: split-(dir,K) all-plane MFMA + reduce
  gemm_outproj_pl<<<dim3(768), blk, 0, stream>>>(yh, yl, o0h, o0l, o1h, o1l, opartial);
  outproj_reduce<<<dim3((unsigned)(M * (long)D_MODEL / 4 / 256)), blk, 0, stream>>>(opartial, out);
}

// Round 15
// 411.130 us; speedup vs baseline: 1.0224x; 1.0224x over previous
//
#include <hip/hip_runtime.h>
#include <hip/hip_bf16.h>
#include <math.h>

#define L_SEQ 2048
#define B_SZ 2
#define D_MODEL 768
#define D_INNER 1536
#define D_STATE 16
#define DT_RANK 48
#define TC 64
#define NC (L_SEQ / TC)          // 32 chunks
#define NDG (D_INNER / 256)      // 6 d-groups
#define NSPL 4
#define KCH (D_INNER / NSPL)     // 384

typedef short bf16x8 __attribute__((ext_vector_type(8)));
typedef float f32x4 __attribute__((ext_vector_type(4)));

#define GLOAD16(g, l) __builtin_amdgcn_global_load_lds( \
    (const __attribute__((address_space(1))) unsigned*)(g), \
    (__attribute__((address_space(3))) unsigned*)(l), 16, 0, 0)

static __device__ __forceinline__ float siluf(float v) {
  return v / (1.0f + __expf(-v));
}
static __device__ __forceinline__ float softplusf(float v) {
  return fmaxf(v, 0.0f) + log1pf(__expf(-fabsf(v)));
}
static __device__ __forceinline__ unsigned short f2bf_rn(float v) {
  unsigned u = __float_as_uint(v);
  u = (u + 0x7fff + ((u >> 16) & 1)) >> 16;
  return (unsigned short)u;
}
static __device__ __forceinline__ float bf2f(unsigned short v) {
  return __uint_as_float((unsigned)v << 16);
}
// 4-way-split dt dot product over one dbl row
static __device__ __forceinline__ float dtdot48(const float* __restrict__ br,
                                                const float* __restrict__ wreg) {
  float a0 = 0.f, a1 = 0.f, a2 = 0.f, a3 = 0.f;
  #pragma unroll
  for (int q = 0; q < 3; ++q) {
    float4 v0 = *(const float4*)(br + q * 16 + 0);
    float4 v1 = *(const float4*)(br + q * 16 + 4);
    float4 v2 = *(const float4*)(br + q * 16 + 8);
    float4 v3 = *(const float4*)(br + q * 16 + 12);
    const float* w = wreg + q * 16;
    a0 = fmaf(v0.x, w[0], a0);  a0 = fmaf(v0.y, w[1], a0);
    a0 = fmaf(v0.z, w[2], a0);  a0 = fmaf(v0.w, w[3], a0);
    a1 = fmaf(v1.x, w[4], a1);  a1 = fmaf(v1.y, w[5], a1);
    a1 = fmaf(v1.z, w[6], a1);  a1 = fmaf(v1.w, w[7], a1);
    a2 = fmaf(v2.x, w[8], a2);  a2 = fmaf(v2.y, w[9], a2);
    a2 = fmaf(v2.z, w[10], a2); a2 = fmaf(v2.w, w[11], a2);
    a3 = fmaf(v3.x, w[12], a3); a3 = fmaf(v3.y, w[13], a3);
    a3 = fmaf(v3.z, w[14], a3); a3 = fmaf(v3.w, w[15], a3);
  }
  return (a0 + a1) + (a2 + a3);
}

// -------- fused fp32 -> bf16 hi/lo conversion for all 7 tensors -----------
__global__ __launch_bounds__(256) void cvt_all(
    const float* __restrict__ s_h,  unsigned short* __restrict__ hh,  unsigned short* __restrict__ hl,
    const float* __restrict__ s_w0, unsigned short* __restrict__ w0h, unsigned short* __restrict__ w0l,
    const float* __restrict__ s_w1, unsigned short* __restrict__ w1h, unsigned short* __restrict__ w1l,
    const float* __restrict__ s_o0, unsigned short* __restrict__ o0h, unsigned short* __restrict__ o0l,
    const float* __restrict__ s_o1, unsigned short* __restrict__ o1h, unsigned short* __restrict__ o1l,
    const float* __restrict__ s_x0, unsigned short* __restrict__ x0h, unsigned short* __restrict__ x0l,
    const float* __restrict__ s_x1, unsigned short* __restrict__ x1h, unsigned short* __restrict__ x1l)
{
  long j = (long)blockIdx.x * 256 + threadIdx.x;   // float4 index
  const long N0 = 786432, N1 = 589824, N2 = 589824, N3 = 294912, N4 = 294912, N5 = 30720;
  const float* src; unsigned short *dh, *dl;
  if (j < N0) { src = s_h; dh = hh; dl = hl; }
  else if ((j -= N0) < N1) { src = s_w0; dh = w0h; dl = w0l; }
  else if ((j -= N1) < N2) { src = s_w1; dh = w1h; dl = w1l; }
  else if ((j -= N2) < N3) { src = s_o0; dh = o0h; dl = o0l; }
  else if ((j -= N3) < N4) { src = s_o1; dh = o1h; dl = o1l; }
  else if ((j -= N4) < N5) { src = s_x0; dh = x0h; dl = x0l; }
  else { j -= N5; src = s_x1; dh = x1h; dl = x1l; }
  float4 v = ((const float4*)src)[j];
  float vv[4] = {v.x, v.y, v.z, v.w};
  unsigned short h4[4], l4[4];
  #pragma unroll
  for (int e = 0; e < 4; ++e) {
    unsigned short hv = f2bf_rn(vv[e]);
    h4[e] = hv;
    l4[e] = f2bf_rn(vv[e] - bf2f(hv));
  }
  uint2 ph, pl;
  ph.x = (unsigned)h4[0] | ((unsigned)h4[1] << 16);
  ph.y = (unsigned)h4[2] | ((unsigned)h4[3] << 16);
  pl.x = (unsigned)l4[0] | ((unsigned)l4[1] << 16);
  pl.y = (unsigned)l4[2] | ((unsigned)l4[3] << 16);
  *(uint2*)&dh[j * 4] = ph;
  *(uint2*)&dl[j * 4] = pl;
}

// -------- in_proj: bf16-plane MFMA GEMM, global_load_lds staging ----------
__global__ __launch_bounds__(256) void gemm_inproj(
    const unsigned short* __restrict__ hh, const unsigned short* __restrict__ hl,
    const unsigned short* __restrict__ w0h, const unsigned short* __restrict__ w0l,
    const unsigned short* __restrict__ w1h, const unsigned short* __restrict__ w1l,
    float* __restrict__ xpre, float* __restrict__ zbuf)
{
  __shared__ unsigned short Ah[128 * 32], Al[128 * 32];
  __shared__ unsigned short Wh[128 * 32], Wl[128 * 32];
  const long S1 = (long)B_SZ * L_SEQ * D_INNER;
  const int tid = threadIdx.x;
  const int lane = tid & 63, w = tid >> 6;
  int bid = blockIdx.x;
  int swz = (bid & 7) * 192 + (bid >> 3);
  int dir = swz / 768;
  int rem = swz - dir * 768;
  int mb = rem / 24, nb = rem - (rem / 24) * 24;
  const int m0 = mb * 128, n0 = nb * 128;
  const unsigned short* Whp = dir ? w1h : w0h;
  const unsigned short* Wlp = dir ? w1l : w0l;
  const int ksl = (lane & 3) ^ ((lane >> 3) & 3);
  long aoff[2], woff[2];
  int ldsc[2];
  #pragma unroll
  for (int qq = 0; qq < 2; ++qq) {
    int cq = w * 2 + qq;
    int r = cq * 16 + (lane >> 2);
    int mr = m0 + r;
    int row = dir ? ((mr & ~(L_SEQ - 1)) | ((L_SEQ - 1) - (mr & (L_SEQ - 1)))) : mr;
    aoff[qq] = (long)row * D_MODEL + 8 * ksl;
    woff[qq] = (long)(n0 + r) * D_MODEL + 8 * ksl;
    ldsc[qq] = cq * 512;
  }
  f32x4 acc[4][4];
  #pragma unroll
  for (int i = 0; i < 4; ++i)
    #pragma unroll
    for (int j = 0; j < 4; ++j) acc[i][j] = (f32x4){0.f, 0.f, 0.f, 0.f};
  const int fr = lane & 15, sl = lane >> 4;
  const int wr = w >> 1, wc = w & 1;
  int roffA[4], roffW[4];
  #pragma unroll
  for (int f = 0; f < 4; ++f) {
    int rA = wr * 64 + f * 16 + fr;
    roffA[f] = rA * 32 + ((sl ^ ((rA >> 1) & 3)) * 8);
    int rW = wc * 64 + f * 16 + fr;
    roffW[f] = rW * 32 + ((sl ^ ((rW >> 1) & 3)) * 8);
  }
  for (int k0 = 0; k0 < D_MODEL; k0 += 32) {
    __syncthreads();
    #pragma unroll
    for (int qq = 0; qq < 2; ++qq) {
      GLOAD16(hh + aoff[qq] + k0, &Ah[ldsc[qq]]);
      GLOAD16(hl + aoff[qq] + k0, &Al[ldsc[qq]]);
      GLOAD16(Whp + woff[qq] + k0, &Wh[ldsc[qq]]);
      GLOAD16(Wlp + woff[qq] + k0, &Wl[ldsc[qq]]);
    }
    __syncthreads();
    bf16x8 afh[4], afl[4];
    #pragma unroll
    for (int f = 0; f < 4; ++f) {
      afh[f] = *(const bf16x8*)&Ah[roffA[f]];
      afl[f] = *(const bf16x8*)&Al[roffA[f]];
    }
    #pragma unroll
    for (int fj = 0; fj < 4; ++fj) {
      bf16x8 wfh = *(const bf16x8*)&Wh[roffW[fj]];
      bf16x8 wfl = *(const bf16x8*)&Wl[roffW[fj]];
      #pragma unroll
      for (int fi = 0; fi < 4; ++fi) {
        acc[fi][fj] = __builtin_amdgcn_mfma_f32_16x16x32_bf16(afh[fi], wfh, acc[fi][fj], 0, 0, 0);
        acc[fi][fj] = __builtin_amdgcn_mfma_f32_16x16x32_bf16(afh[fi], wfl, acc[fi][fj], 0, 0, 0);
        acc[fi][fj] = __builtin_amdgcn_mfma_f32_16x16x32_bf16(afl[fi], wfh, acc[fi][fj], 0, 0, 0);
      }
    }
  }
  float* xq = xpre + (long)dir * S1;
  float* zq = zbuf + (long)dir * S1;
  const int fcol = lane & 15, rgrp = lane >> 4;
  #pragma unroll
  for (int fi = 0; fi < 4; ++fi) {
    #pragma unroll
    for (int j = 0; j < 4; ++j) {
      int row = m0 + wr * 64 + fi * 16 + rgrp * 4 + j;
      #pragma unroll
      for (int fj = 0; fj < 4; ++fj) {
        int n = n0 + wc * 64 + fj * 16 + fcol;
        float v = acc[fi][fj][j];
        if (n < D_INNER) xq[(long)row * D_INNER + n] = v;
        else             zq[(long)row * D_INNER + (n - D_INNER)] = v;
      }
    }
  }
}

// -------- xproj: plane MFMA, N=80 padded to 128, split-K x4 ---------------
__global__ __launch_bounds__(256) void xproj_mfma(
    const unsigned short* __restrict__ xh, const unsigned short* __restrict__ xl,
    const unsigned short* __restrict__ x0h, const unsigned short* __restrict__ x0l,
    const unsigned short* __restrict__ x1h, const unsigned short* __restrict__ x1l,
    float* __restrict__ partial)   // [2*NSPL][4096][80]
{
  __shared__ unsigned short Ah[128 * 32], Al[128 * 32];
  __shared__ unsigned short Wh[128 * 32], Wl[128 * 32];
  const long S1 = (long)B_SZ * L_SEQ * D_INNER;
  const int tid = threadIdx.x;
  const int lane = tid & 63, w = tid >> 6;
  int bid = blockIdx.x;
  int dir = bid >> 7;
  int kz = (bid >> 5) & 3;
  int mb = bid & 31;
  const int m0 = mb * 128;
  const int kbase = kz * KCH;
  const unsigned short* Ahp = xh + (long)dir * S1;
  const unsigned short* Alp = xl + (long)dir * S1;
  const unsigned short* Whp = dir ? x1h : x0h;
  const unsigned short* Wlp = dir ? x1l : x0l;
  const int ksl = (lane & 3) ^ ((lane >> 3) & 3);
  long aoff[2], woff[2];
  int ldsc[2], cqv[2];
  #pragma unroll
  for (int qq = 0; qq < 2; ++qq) {
    int cq = w * 2 + qq;
    int r = cq * 16 + (lane >> 2);
    aoff[qq] = (long)(m0 + r) * D_INNER + 8 * ksl + kbase;
    woff[qq] = (long)r * D_INNER + 8 * ksl + kbase;
    ldsc[qq] = cq * 512;
    cqv[qq] = cq;
  }
  for (int i = tid; i < 48 * 32; i += 256) { Wh[80 * 32 + i] = 0; Wl[80 * 32 + i] = 0; }
  f32x4 acc[4][4];
  #pragma unroll
  for (int i = 0; i < 4; ++i)
    #pragma unroll
    for (int j = 0; j < 4; ++j) acc[i][j] = (f32x4){0.f, 0.f, 0.f, 0.f};
  const int fr = lane & 15, sl = lane >> 4;
  const int wr = w >> 1, wc = w & 1;
  int roffA[4], roffW[4];
  #pragma unroll
  for (int f = 0; f < 4; ++f) {
    int rA = wr * 64 + f * 16 + fr;
    roffA[f] = rA * 32 + ((sl ^ ((rA >> 1) & 3)) * 8);
    int rW = wc * 64 + f * 16 + fr;
    roffW[f] = rW * 32 + ((sl ^ ((rW >> 1) & 3)) * 8);
  }
  for (int k0 = 0; k0 < KCH; k0 += 32) {
    __syncthreads();
    #pragma unroll
    for (int qq = 0; qq < 2; ++qq) {
      GLOAD16(Ahp + aoff[qq] + k0, &Ah[ldsc[qq]]);
      GLOAD16(Alp + aoff[qq] + k0, &Al[ldsc[qq]]);
      if (cqv[qq] < 5) {
        GLOAD16(Whp + woff[qq] + k0, &Wh[ldsc[qq]]);
        GLOAD16(Wlp + woff[qq] + k0, &Wl[ldsc[qq]]);
      }
    }
    __syncthreads();
    bf16x8 afh[4], afl[4];
    #pragma unroll
    for (int f = 0; f < 4; ++f) {
      afh[f] = *(const bf16x8*)&Ah[roffA[f]];
      afl[f] = *(const bf16x8*)&Al[roffA[f]];
    }
    #pragma unroll
    for (int fj = 0; fj < 4; ++fj) {
      bf16x8 wfh = *(const bf16x8*)&Wh[roffW[fj]];
      bf16x8 wfl = *(const bf16x8*)&Wl[roffW[fj]];
      #pragma unroll
      for (int fi = 0; fi < 4; ++fi) {
        acc[fi][fj] = __builtin_amdgcn_mfma_f32_16x16x32_bf16(afh[fi], wfh, acc[fi][fj], 0, 0, 0);
        acc[fi][fj] = __builtin_amdgcn_mfma_f32_16x16x32_bf16(afh[fi], wfl, acc[fi][fj], 0, 0, 0);
        acc[fi][fj] = __builtin_amdgcn_mfma_f32_16x16x32_bf16(afl[fi], wfh, acc[fi][fj], 0, 0, 0);
      }
    }
  }
  float* P = partial + (long)(dir * NSPL + kz) * (B_SZ * L_SEQ) * 80;
  const int fcol = lane & 15, rgrp = lane >> 4;
  #pragma unroll
  for (int fi = 0; fi < 4; ++fi) {
    #pragma unroll
    for (int j = 0; j < 4; ++j) {
      int row = m0 + wr * 64 + fi * 16 + rgrp * 4 + j;
      #pragma unroll
      for (int fj = 0; fj < 4; ++fj) {
        int n = wc * 64 + fj * 16 + fcol;
        if (n < 80) P[(long)row * 80 + n] = acc[fi][fj][j];
      }
    }
  }
}

__global__ __launch_bounds__(256) void xproj_reduce(
    const float* __restrict__ partial, float* __restrict__ dbl)
{
  long idx = (long)blockIdx.x * 256 + threadIdx.x;
  const long plane = (long)B_SZ * L_SEQ * 80;
  long dir = idx / plane;
  long rc = idx % plane;
  const float* P = partial + dir * NSPL * plane + rc;
  float s = 0.f;
  #pragma unroll
  for (int z = 0; z < NSPL; ++z) s += P[z * plane];
  dbl[idx] = s;
}

// -------- dtproj: slot-dense dt precompute (thread = (dir,d), 32 rows) ----
__global__ __launch_bounds__(256) void dtproj_k(
    const float* __restrict__ dbl,
    const float* __restrict__ dtw_f, const float* __restrict__ dtw_r,
    const float* __restrict__ dtb_f, const float* __restrict__ dtb_r,
    float* __restrict__ dt)   // [2][B*L][D_INNER]
{
  const int tid = threadIdx.x;
  const int dgrp = blockIdx.x;            // 0..11 = dir*NDG + dg
  const int dir = dgrp / NDG;
  const int d = (dgrp % NDG) * 256 + tid;
  const int rc = blockIdx.y;              // 0..63, 32 rows each
  const float* dtw = dir ? dtw_r : dtw_f;
  const float dtbv = (dir ? dtb_r : dtb_f)[d];
  float wreg[48];
  #pragma unroll
  for (int q = 0; q < 12; ++q)
    *(float4*)&wreg[q * 4] = *(const float4*)&dtw[d * DT_RANK + q * 4];
  const long rowbase = (long)dir * (B_SZ * L_SEQ) + (long)rc * 32;
  for (int r = 0; r < 32; ++r) {
    long row = rowbase + r;
    const float* br = dbl + row * 80;
    float v = softplusf(dtdot48(br, wreg) + dtbv);
    dt[row * D_INNER + d] = v;
  }
}

// -------- out_proj: all-plane MFMA; split-(dir,K); GLOAD16 staging --------
__global__ __launch_bounds__(256) void gemm_outproj_pl(
    const unsigned short* __restrict__ yh, const unsigned short* __restrict__ yl,
    const unsigned short* __restrict__ o0h, const unsigned short* __restrict__ o0l,
    const unsigned short* __restrict__ o1h, const unsigned short* __restrict__ o1l,
    float* __restrict__ partial)   // [4][4096][768], plane = dir*2+ks
{
  __shared__ unsigned short Ah[128 * 32], Al[128 * 32];
  __shared__ unsigned short Wh[128 * 32], Wl[128 * 32];
  const long S1 = (long)B_SZ * L_SEQ * D_INNER;
  const int tid = threadIdx.x;
  const int lane = tid & 63, w = tid >> 6;
  int bid = blockIdx.x;
  int swz = (bid & 7) * 96 + (bid >> 3);
  int dir = swz / 384;
  int r1 = swz - dir * 384;
  int ks = r1 / 192;
  int r2 = r1 - ks * 192;
  int mb = r2 / 6, nb = r2 - (r2 / 6) * 6;
  const int m0 = mb * 128, n0 = nb * 128;
  const int kbase = ks * (D_INNER / 2);
  const unsigned short* Ahp = yh + (long)dir * S1;
  const unsigned short* Alp = yl + (long)dir * S1;
  const unsigned short* Whp = dir ? o1h : o0h;
  const unsigned short* Wlp = dir ? o1l : o0l;
  const int ksl = (lane & 3) ^ ((lane >> 3) & 3);
  long aoff[2], woff[2];
  int ldsc[2];
  #pragma unroll
  for (int qq = 0; qq < 2; ++qq) {
    int cq = w * 2 + qq;
    int r = cq * 16 + (lane >> 2);
    int mr = m0 + r;
    int row = dir ? ((mr & ~(L_SEQ - 1)) | ((L_SEQ - 1) - (mr & (L_SEQ - 1)))) : mr;
    aoff[qq] = (long)row * D_INNER + 8 * ksl + kbase;
    woff[qq] = (long)(n0 + r) * D_INNER + 8 * ksl + kbase;
    ldsc[qq] = cq * 512;
  }
  f32x4 acc[4][4];
  #pragma unroll
  for (int i = 0; i < 4; ++i)
    #pragma unroll
    for (int j = 0; j < 4; ++j) acc[i][j] = (f32x4){0.f, 0.f, 0.f, 0.f};
  const int fr = lane & 15, sl = lane >> 4;
  const int wr = w >> 1, wc = w & 1;
  int roffA[4], roffW[4];
  #pragma unroll
  for (int f = 0; f < 4; ++f) {
    int rA = wr * 64 + f * 16 + fr;
    roffA[f] = rA * 32 + ((sl ^ ((rA >> 1) & 3)) * 8);
    int rW = wc * 64 + f * 16 + fr;
    roffW[f] = rW * 32 + ((sl ^ ((rW >> 1) & 3)) * 8);
  }
  for (int k0 = 0; k0 < D_INNER / 2; k0 += 32) {
    __syncthreads();
    #pragma unroll
    for (int qq = 0; qq < 2; ++qq) {
      GLOAD16(Ahp + aoff[qq] + k0, &Ah[ldsc[qq]]);
      GLOAD16(Alp + aoff[qq] + k0, &Al[ldsc[qq]]);
      GLOAD16(Whp + woff[qq] + k0, &Wh[ldsc[qq]]);
      GLOAD16(Wlp + woff[qq] + k0, &Wl[ldsc[qq]]);
    }
    __syncthreads();
    bf16x8 afh[4], afl[4];
    #pragma unroll
    for (int f = 0; f < 4; ++f) {
      afh[f] = *(const bf16x8*)&Ah[roffA[f]];
      afl[f] = *(const bf16x8*)&Al[roffA[f]];
    }
    #pragma unroll
    for (int fj = 0; fj < 4; ++fj) {
      bf16x8 wfh = *(const bf16x8*)&Wh[roffW[fj]];
      bf16x8 wfl = *(const bf16x8*)&Wl[roffW[fj]];
      #pragma unroll
      for (int fi = 0; fi < 4; ++fi) {
        acc[fi][fj] = __builtin_amdgcn_mfma_f32_16x16x32_bf16(afh[fi], wfh, acc[fi][fj], 0, 0, 0);
        acc[fi][fj] = __builtin_amdgcn_mfma_f32_16x16x32_bf16(afh[fi], wfl, acc[fi][fj], 0, 0, 0);
        acc[fi][fj] = __builtin_amdgcn_mfma_f32_16x16x32_bf16(afl[fi], wfh, acc[fi][fj], 0, 0, 0);
      }
    }
  }
  float* P = partial + (long)(dir * 2 + ks) * (B_SZ * L_SEQ) * D_MODEL;
  const int fcol = lane & 15, rgrp = lane >> 4;
  #pragma unroll
  for (int fi = 0; fi < 4; ++fi) {
    #pragma unroll
    for (int j = 0; j < 4; ++j) {
      int row = m0 + wr * 64 + fi * 16 + rgrp * 4 + j;
      #pragma unroll
      for (int fj = 0; fj < 4; ++fj) {
        int n = n0 + wc * 64 + fj * 16 + fcol;
        P[(long)row * D_MODEL + n] = acc[fi][fj][j];
      }
    }
  }
}

__global__ __launch_bounds__(256) void outproj_reduce(
    const float* __restrict__ partial, float* __restrict__ out)
{
  long i = (long)blockIdx.x * 256 + threadIdx.x;   // float4 index
  const long plane4 = (long)B_SZ * L_SEQ * D_MODEL / 4;  // 786432
  float4 a = ((const float4*)partial)[i];
  float4 b = ((const float4*)partial)[i + plane4];
  float4 c = ((const float4*)partial)[i + 2 * plane4];
  float4 d = ((const float4*)partial)[i + 3 * plane4];
  float4 s;
  s.x = (a.x + b.x) + (c.x + d.x);
  s.y = (a.y + b.y) + (c.y + d.y);
  s.z = (a.z + b.z) + (c.z + d.z);
  s.w = (a.w + b.w) + (c.w + d.w);
  ((float4*)out)[i] = s;
}

// -------- conv (w=4) + bias + silu -> bf16 planes; 4 timesteps/thread -----
__global__ __launch_bounds__(256) void conv_silu_pl4(
    const float* __restrict__ xpre,
    const float* __restrict__ w_f, const float* __restrict__ b_f,
    const float* __restrict__ w_r, const float* __restrict__ b_r,
    unsigned short* __restrict__ xh, unsigned short* __restrict__ xl)
{
  long i = (long)blockIdx.x * 256 + threadIdx.x;
  const int DQ = D_INNER / 4;                 // 384
  const long total = 2L * B_SZ * (L_SEQ / 4) * DQ;   // 786432
  if (i >= total) return;
  int dq = (int)(i % DQ);
  long rq = i / DQ;
  int t0 = (int)((rq & (L_SEQ / 4 - 1)) * 4);
  long rbase = (rq >> 9) * L_SEQ;
  int dir = (int)(rq >> 10);
  int d0 = dq * 4;
  const float* w  = dir ? w_r : w_f;
  const float* cb = dir ? b_r : b_f;
  float4 bias = *(const float4*)&cb[d0];
  float4 wc[4];
  #pragma unroll
  for (int c = 0; c < 4; ++c) wc[c] = *(const float4*)&w[(d0 + c) * 4];
  float4 xrow[7];
  #pragma unroll
  for (int j = 0; j < 7; ++j) {
    int tv = t0 + j - 3;
    if (tv >= 0) xrow[j] = *(const float4*)&xpre[(rbase + tv) * D_INNER + d0];
    else xrow[j] = (float4){0.f, 0.f, 0.f, 0.f};
  }
  #pragma unroll
  for (int u = 0; u < 4; ++u) {
    float4 a = bias;
    #pragma unroll
    for (int k = 0; k < 4; ++k) {
      float4 xv = xrow[u + k];
      a.x = fmaf(((const float*)&wc[0])[k], xv.x, a.x);
      a.y = fmaf(((const float*)&wc[1])[k], xv.y, a.y);
      a.z = fmaf(((const float*)&wc[2])[k], xv.z, a.z);
      a.w = fmaf(((const float*)&wc[3])[k], xv.w, a.w);
    }
    float vv[4] = {siluf(a.x), siluf(a.y), siluf(a.z), siluf(a.w)};
    unsigned short h4[4], l4[4];
    #pragma unroll
    for (int e = 0; e < 4; ++e) {
      unsigned short hv = f2bf_rn(vv[e]);
      h4[e] = hv;
      l4[e] = f2bf_rn(vv[e] - bf2f(hv));
    }
    uint2 ph, pl;
    ph.x = (unsigned)h4[0] | ((unsigned)h4[1] << 16);
    ph.y = (unsigned)h4[2] | ((unsigned)h4[3] << 16);
    pl.x = (unsigned)l4[0] | ((unsigned)l4[1] << 16);
    pl.y = (unsigned)l4[2] | ((unsigned)l4[3] << 16);
    long off = (rbase + t0 + u) * D_INNER + d0;
    *(uint2*)&xh[off] = ph;
    *(uint2*)&xl[off] = pl;
  }
}

// -------- scan pass 1, dt PRELOADED ---------------------------------------
__global__ __launch_bounds__(256, 3) void scan_mega1(
    const unsigned short* __restrict__ xh, const unsigned short* __restrict__ xl,
    const float* __restrict__ dbl, const float* __restrict__ dt,
    const float* __restrict__ A_log_f, const float* __restrict__ A_log_r,
    float* __restrict__ stateS, float* __restrict__ stateP)
{
  const int tid = threadIdx.x;
  const int chunk = blockIdx.x / NDG;
  const int d = (blockIdx.x % NDG) * 256 + tid;
  const int b = blockIdx.y, dir = blockIdx.z;
  const float* A_log = dir ? A_log_r : A_log_f;
  float Arow[D_STATE];
  #pragma unroll
  for (int n = 0; n < D_STATE; ++n) Arow[n] = -expf(A_log[d * D_STATE + n]);
  float h[D_STATE], P[D_STATE];
  #pragma unroll
  for (int n = 0; n < D_STATE; ++n) { h[n] = 0.f; P[n] = 1.f; }
  const long rowbase = ((long)dir * B_SZ + b) * L_SEQ + (long)chunk * TC;
  for (int tj = 0; tj < TC; ++tj) {
    const float* br = dbl + (rowbase + tj) * 80;
    long off = (rowbase + tj) * D_INNER + d;
    float dtv = dt[off];
    float xv = bf2f(xh[off]) + bf2f(xl[off]);
    float dtx = dtv * xv;
    float bc[D_STATE];
    #pragma unroll
    for (int q = 0; q < 4; ++q)
      *(float4*)&bc[q * 4] = *(const float4*)(br + 48 + q * 4);
    #pragma unroll
    for (int n = 0; n < D_STATE; ++n) {
      float dA = __expf(dtv * Arow[n]);
      P[n] *= dA;
      h[n] = fmaf(h[n], dA, dtx * bc[n]);
    }
  }
  long base = ((((long)dir * B_SZ + b) * NC + chunk) * D_INNER + d) * D_STATE;
  #pragma unroll
  for (int n = 0; n < D_STATE; ++n) { stateS[base + n] = h[n]; stateP[base + n] = P[n]; }
}

// -------- fused-dt fallback variant of pass 1 -----------------------------
__global__ __launch_bounds__(256, 3) void scan_mega1_f(
    const unsigned short* __restrict__ xh, const unsigned short* __restrict__ xl,
    const float* __restrict__ dbl,
    const float* __restrict__ dtw_f, const float* __restrict__ dtw_r,
    const float* __restrict__ dtb_f, const float* __restrict__ dtb_r,
    const float* __restrict__ A_log_f, const float* __restrict__ A_log_r,
    float* __restrict__ stateS, float* __restrict__ stateP)
{
  const int tid = threadIdx.x;
  const int chunk = blockIdx.x / NDG;
  const int d = (blockIdx.x % NDG) * 256 + tid;
  const int b = blockIdx.y, dir = blockIdx.z;
  const float* A_log = dir ? A_log_r : A_log_f;
  const float* dtw   = dir ? dtw_r : dtw_f;
  const float dtbv   = (dir ? dtb_r : dtb_f)[d];
  float wreg[48];
  #pragma unroll
  for (int q = 0; q < 12; ++q)
    *(float4*)&wreg[q * 4] = *(const float4*)&dtw[d * DT_RANK + q * 4];
  float Arow[D_STATE];
  #pragma unroll
  for (int n = 0; n < D_STATE; ++n) Arow[n] = -expf(A_log[d * D_STATE + n]);
  float h[D_STATE], P[D_STATE];
  #pragma unroll
  for (int n = 0; n < D_STATE; ++n) { h[n] = 0.f; P[n] = 1.f; }
  const long rowbase = ((long)dir * B_SZ + b) * L_SEQ + (long)chunk * TC;
  for (int tj = 0; tj < TC; ++tj) {
    const float* br = dbl + (rowbase + tj) * 80;
    float dtv = softplusf(dtdot48(br, wreg) + dtbv);
    long off = (rowbase + tj) * D_INNER + d;
    float xv = bf2f(xh[off]) + bf2f(xl[off]);
    float dtx = dtv * xv;
    float bc[D_STATE];
    #pragma unroll
    for (int q = 0; q < 4; ++q)
      *(float4*)&bc[q * 4] = *(const float4*)(br + 48 + q * 4);
    #pragma unroll
    for (int n = 0; n < D_STATE; ++n) {
      float dA = __expf(dtv * Arow[n]);
      P[n] *= dA;
      h[n] = fmaf(h[n], dA, dtx * bc[n]);
    }
  }
  long base = ((((long)dir * B_SZ + b) * NC + chunk) * D_INNER + d) * D_STATE;
  #pragma unroll
  for (int n = 0; n < D_STATE; ++n) { stateS[base + n] = h[n]; stateP[base + n] = P[n]; }
}

// -------- fix-up: all chunk (S,P) in registers, short chain ---------------
__global__ __launch_bounds__(256) void scan_fix(
    float* __restrict__ stateS, const float* __restrict__ stateP)
{
  const long idx = (long)blockIdx.x * 256 + threadIdx.x;
  const int DN = D_INNER * D_STATE;
  const long dirb = idx / DN;
  const int dn = (int)(idx % DN);
  long base = dirb * NC * DN + dn;
  float S[NC], P[NC];
  #pragma unroll
  for (int c = 0; c < NC; ++c) {
    S[c] = stateS[base + (long)c * DN];
    P[c] = stateP[base + (long)c * DN];
  }
  float h = 0.f;
  #pragma unroll
  for (int c = 0; c < NC; ++c) {
    stateS[base + (long)c * DN] = h;
    h = fmaf(h, P[c], S[c]);
  }
}

// -------- scan pass 2 + gating + y planes, dt PRELOADED -------------------
__global__ __launch_bounds__(256, 3) void scan_mega2(
    const unsigned short* __restrict__ xh, const unsigned short* __restrict__ xl,
    const float* __restrict__ dbl, const float* __restrict__ z,
    const float* __restrict__ dt,
    const float* __restrict__ A_log_f, const float* __restrict__ A_log_r,
    const float* __restrict__ Ds_f, const float* __restrict__ Ds_r,
    const float* __restrict__ stateS,
    unsigned short* __restrict__ yh, unsigned short* __restrict__ yl)
{
  const int tid = threadIdx.x;
  const int chunk = blockIdx.x / NDG;
  const int d = (blockIdx.x % NDG) * 256 + tid;
  const int b = blockIdx.y, dir = blockIdx.z;
  const float* A_log = dir ? A_log_r : A_log_f;
  const float Dd     = (dir ? Ds_r : Ds_f)[d];
  float Arow[D_STATE];
  #pragma unroll
  for (int n = 0; n < D_STATE; ++n) Arow[n] = -expf(A_log[d * D_STATE + n]);
  float h[D_STATE];
  long sbase = ((((long)dir * B_SZ + b) * NC + chunk) * D_INNER + d) * D_STATE;
  #pragma unroll
  for (int n = 0; n < D_STATE; ++n) h[n] = stateS[sbase + n];
  const long rowbase = ((long)dir * B_SZ + b) * L_SEQ + (long)chunk * TC;
  for (int tj = 0; tj < TC; ++tj) {
    const float* br = dbl + (rowbase + tj) * 80;
    long off = (rowbase + tj) * D_INNER + d;
    float dtv = dt[off];
    float xv = bf2f(xh[off]) + bf2f(xl[off]);
    float zv = z[off];
    float dtx = dtv * xv;
    float bc[2 * D_STATE];
    #pragma unroll
    for (int q = 0; q < 8; ++q)
      *(float4*)&bc[q * 4] = *(const float4*)(br + 48 + q * 4);
    float y = 0.f;
    #pragma unroll
    for (int n = 0; n < D_STATE; ++n) {
      float dA = __expf(dtv * Arow[n]);
      h[n] = fmaf(h[n], dA, dtx * bc[n]);
      y = fmaf(h[n], bc[16 + n], y);
    }
    y = fmaf(xv, Dd, y);
    y *= siluf(zv);
    unsigned short hv = f2bf_rn(y);
    yh[off] = hv;
    yl[off] = f2bf_rn(y - bf2f(hv));
  }
}

// -------- fused-dt fallback variant of pass 2 -----------------------------
__global__ __launch_bounds__(256, 3) void scan_mega2_f(
    const unsigned short* __restrict__ xh, const unsigned short* __restrict__ xl,
    const float* __restrict__ dbl, const float* __restrict__ z,
    const float* __restrict__ dtw_f, const float* __restrict__ dtw_r,
    const float* __restrict__ dtb_f, const float* __restrict__ dtb_r,
    const float* __restrict__ A_log_f, const float* __restrict__ A_log_r,
    const float* __restrict__ Ds_f, const float* __restrict__ Ds_r,
    const float* __restrict__ stateS,
    unsigned short* __restrict__ yh, unsigned short* __restrict__ yl)
{
  const int tid = threadIdx.x;
  const int chunk = blockIdx.x / NDG;
  const int d = (blockIdx.x % NDG) * 256 + tid;
  const int b = blockIdx.y, dir = blockIdx.z;
  const float* A_log = dir ? A_log_r : A_log_f;
  const float* dtw   = dir ? dtw_r : dtw_f;
  const float dtbv   = (dir ? dtb_r : dtb_f)[d];
  const float Dd     = (dir ? Ds_r : Ds_f)[d];
  float wreg[48];
  #pragma unroll
  for (int q = 0; q < 12; ++q)
    *(float4*)&wreg[q * 4] = *(const float4*)&dtw[d * DT_RANK + q * 4];
  float Arow[D_STATE];
  #pragma unroll
  for (int n = 0; n < D_STATE; ++n) Arow[n] = -expf(A_log[d * D_STATE + n]);
  float h[D_STATE];
  long sbase = ((((long)dir * B_SZ + b) * NC + chunk) * D_INNER + d) * D_STATE;
  #pragma unroll
  for (int n = 0; n < D_STATE; ++n) h[n] = stateS[sbase + n];
  const long rowbase = ((long)dir * B_SZ + b) * L_SEQ + (long)chunk * TC;
  for (int tj = 0; tj < TC; ++tj) {
    const float* br = dbl + (rowbase + tj) * 80;
    float dtv = softplusf(dtdot48(br, wreg) + dtbv);
    long off = (rowbase + tj) * D_INNER + d;
    float xv = bf2f(xh[off]) + bf2f(xl[off]);
    float zv = z[off];
    float dtx = dtv * xv;
    float bc[2 * D_STATE];
    #pragma unroll
    for (int q = 0; q < 8; ++q)
      *(float4*)&bc[q * 4] = *(const float4*)(br + 48 + q * 4);
    float y = 0.f;
    #pragma unroll
    for (int n = 0; n < D_STATE; ++n) {
      float dA = __expf(dtv * Arow[n]);
      h[n] = fmaf(h[n], dA, dtx * bc[n]);
      y = fmaf(h[n], bc[16 + n], y);
    }
    y = fmaf(xv, Dd, y);
    y *= siluf(zv);
    unsigned short hv = f2bf_rn(y);
    yh[off] = hv;
    yl[off] = f2bf_rn(y - bf2f(hv));
  }
}

extern "C" void kernel_launch(void* const* d_in, const int* in_sizes, int n_in,
                              void* d_out, int out_size, void* d_ws, size_t ws_size,
                              hipStream_t stream) {
  const float* h        = (const float*)d_in[0];
  const float* in_proj[2] = {(const float*)d_in[1], (const float*)d_in[10]};
  const float* conv_w[2]  = {(const float*)d_in[2], (const float*)d_in[11]};
  const float* conv_b[2]  = {(const float*)d_in[3], (const float*)d_in[12]};
  const float* xproj[2]   = {(const float*)d_in[4], (const float*)d_in[13]};
  const float* dtw[2]     = {(const float*)d_in[5], (const float*)d_in[14]};
  const float* dtb[2]     = {(const float*)d_in[6], (const float*)d_in[15]};
  const float* A_log[2]   = {(const float*)d_in[7], (const float*)d_in[16]};
  const float* Dsk[2]     = {(const float*)d_in[8], (const float*)d_in[17]};
  const float* outp[2]    = {(const float*)d_in[9], (const float*)d_in[18]};
  float* out = (float*)d_out;
  float* ws = (float*)d_ws;

  const long S1 = (long)B_SZ * L_SEQ * D_INNER;   // 6,291,456
  const int M = B_SZ * L_SEQ;                     // 4096
  float* xpre  = ws;
  float* zbuf  = ws + 2 * S1;
  float* xconv = ws + 4 * S1;
  float* dbl   = ws + 6 * S1;
  float* base4 = dbl + 2L * M * 80;

  unsigned short* hh  = (unsigned short*)base4;             // 3,145,728 each
  unsigned short* hl  = hh + 3145728;
  unsigned short* w0h = hl + 3145728;                       // 2,359,296 each
  unsigned short* w0l = w0h + 2359296;
  unsigned short* w1h = w0l + 2359296;
  unsigned short* w1l = w1h + 2359296;
  unsigned short* o0h = w1l + 2359296;                      // 1,179,648 each
  unsigned short* o0l = o0h + 1179648;
  unsigned short* o1h = o0l + 1179648;
  unsigned short* o1l = o1h + 1179648;
  float* xpartial = base4;
  float* stS = base4;                // 3.15M fl
  float* stP = stS + 3145728;        // 3.15M fl
  unsigned short* xw0h = (unsigned short*)dbl;              // 122,880 each
  unsigned short* xw0l = xw0h + 122880;
  unsigned short* xw1h = xw0l + 122880;
  unsigned short* xw1l = xw1h + 122880;
  unsigned short* xph = (unsigned short*)xconv;
  unsigned short* xpl = xph + 2 * S1;
  unsigned short* yh = (unsigned short*)xpre;
  unsigned short* yl = yh + 2 * S1;
  float* opartial = xconv;

  // dt buffer in EXTENDED workspace, past o1l; guarded by ws_size.
  float* dtbuf = base4 + 10223616;             // o1l end (20,447,232 ushorts)
  const long need_fl = (6 * S1) + 2L * M * 80 + 10223616 + 2 * S1;  // +dt
  const bool use_dt = (ws_size >= (size_t)need_fl * 4);

  dim3 blk(256);

  // 0. pre-convert h + all GEMM weights to bf16 hi/lo planes
  cvt_all<<<dim3(10224), blk, 0, stream>>>(
      h, hh, hl, in_proj[0], w0h, w0l, in_proj[1], w1h, w1l,
      outp[0], o0h, o0l, outp[1], o1h, o1l,
      xproj[0], xw0h, xw0l, xproj[1], xw1h, xw1l);

  // 1. in_proj (both dirs) -> x (pre-conv, fp32) and z
  gemm_inproj<<<dim3(1536), blk, 0, stream>>>(hh, hl, w0h, w0l, w1h, w1l, xpre, zbuf);

  // 2. conv + silu -> x bf16 hi/lo planes
  conv_silu_pl4<<<dim3(3072), blk, 0, stream>>>(
      xpre, conv_w[0], conv_b[0], conv_w[1], conv_b[1], xph, xpl);

  // 3. xproj (plane MFMA, split-K x4) -> partials -> dbl
  xproj_mfma<<<dim3(256), blk, 0, stream>>>(xph, xpl, xw0h, xw0l, xw1h, xw1l, xpartial);
  xproj_reduce<<<dim3((unsigned)(2L * M * 80 / 256)), blk, 0, stream>>>(xpartial, dbl);

  // 4+5. dt precompute (if ws allows) + chunked scan
  {
    dim3 grid1(NC * NDG, B_SZ, 2);
    long nfix = 2L * B_SZ * D_INNER * D_STATE;
    if (use_dt) {
      dtproj_k<<<dim3(12, 64), blk, 0, stream>>>(dbl, dtw[0], dtw[1], dtb[0], dtb[1], dtbuf);
      scan_mega1<<<grid1, blk, 0, stream>>>(xph, xpl, dbl, dtbuf,
          A_log[0], A_log[1], stS, stP);
      scan_fix<<<dim3((unsigned)(nfix / 256)), blk, 0, stream>>>(stS, stP);
      scan_mega2<<<grid1, blk, 0, stream>>>(xph, xpl, dbl, zbuf, dtbuf,
          A_log[0], A_log[1], Dsk[0], Dsk[1], stS, yh, yl);
    } else {
      scan_mega1_f<<<grid1, blk, 0, stream>>>(xph, xpl, dbl,
          dtw[0], dtw[1], dtb[0], dtb[1], A_log[0], A_log[1], stS, stP);
      scan_fix<<<dim3((unsigned)(nfix / 256)), blk, 0, stream>>>(stS, stP);
      scan_mega2_f<<<grid1, blk, 0, stream>>>(xph, xpl, dbl, zbuf,
          dtw[0], dtw[1], dtb[0], dtb[1], A_log[0], A_log[1],
          Dsk[0], Dsk[1], stS, yh, yl);
    }
  }
  // 6. out_proj: split-(dir,K) all-plane MFMA + reduce
  gemm_outproj_pl<<<dim3(768), blk, 0, stream>>>(yh, yl, o0h, o0l, o1h, o1l, opartial);
  outproj_reduce<<<dim3((unsigned)(M * (long)D_MODEL / 4 / 256)), blk, 0, stream>>>(opartial, out);
}